// Round 1
// baseline (219.955 us; speedup 1.0000x reference)
//
#include <hip/hip_runtime.h>
#include <math.h>

#define B_ 8
#define C_ 256
#define N_ 4096          // H*W
#define NPOS 32768       // B*N
#define SCALE_ 0.1767766952966369f
#define EPS_ 1e-5f

typedef __attribute__((ext_vector_type(8))) short bf16x8;
typedef __attribute__((ext_vector_type(8))) unsigned short u16x8;
typedef __attribute__((ext_vector_type(4))) float f32x4;

__device__ __forceinline__ unsigned short f2bf(float f) {
  union { float f; unsigned u; } v; v.f = f;
  unsigned r = v.u + 0x7fff + ((v.u >> 16) & 1);   // RNE
  return (unsigned short)(r >> 16);
}
__device__ __forceinline__ float bf2f(unsigned short u) {
  union { unsigned u; float f; } v; v.u = ((unsigned)u) << 16; return v.f;
}
__device__ __forceinline__ float blo(unsigned u) {
  union { unsigned u; float f; } v; v.u = u << 16; return v.f;
}
__device__ __forceinline__ float bhi(unsigned u) {
  union { unsigned u; float f; } v; v.u = u & 0xffff0000u; return v.f;
}

#define GLD_LDS16(g, l) \
  __builtin_amdgcn_global_load_lds((const __attribute__((address_space(1))) unsigned int*)(g), \
                                   (__attribute__((address_space(3))) unsigned int*)(l), 16, 0, 0)

// ---- kernel 1: [blocks 0..255] weight cvt  [blocks 256..1279] sub+LN ----
// sub_ln: writes subB bf16 (BCHW), viB bf16 (BCHW), xn bf16 [NPOS,256]
// v2: bf16 [pos][c^swz] LDS tile (16KB, was 33.8KB f32) -> 8 blocks/CU;
// mean/var from f32 regs via shfl_xor reduce; vectorized 16B xn stores.
__global__ __launch_bounds__(256, 8) void k_pre(
    const float* __restrict__ vi, const float* __restrict__ ir,
    const float* __restrict__ wq, const float* __restrict__ pw,
    const float* __restrict__ ln_g, const float* __restrict__ ln_b,
    unsigned short* __restrict__ wdst,
    unsigned short* __restrict__ subB, unsigned short* __restrict__ viB,
    unsigned short* __restrict__ xn)
{
  __shared__ __align__(16) unsigned short tile[32 * 256];   // [pos][c ^ ((pos>>2)<<3)]
  __shared__ float redS[4][32], redS2[4][32];
  __shared__ float meanS[32], rstdS[32];
  __shared__ float sG[256], sB[256];
  int t = threadIdx.x;
  if (blockIdx.x < 256) {
    int i4 = blockIdx.x * 256 + t;   // 65536 float4s
    float4 v = (i4 < 49152) ? ((const float4*)wq)[i4] : ((const float4*)pw)[i4 - 49152];
    ushort4 o;
    o.x = f2bf(v.x); o.y = f2bf(v.y); o.z = f2bf(v.z); o.w = f2bf(v.w);
    ((ushort4*)wdst)[i4] = o;
    return;
  }
  int blk = blockIdx.x - 256;              // b*128 + y*2 + half
  int b = blk >> 7;
  int y = (blk >> 1) & 63;
  int half = blk & 1;
  size_t base = (size_t)b * C_ * N_ + (size_t)y * 64 + half * 32;
  sG[t] = ln_g[t];
  sB[t] = ln_b[t];
  int g = t >> 3;           // channel subgroup (in-wave bits 0..2 + wave*8)
  int k8 = t & 7;           // position quad index: positions k8*4 .. k8*4+3
  int xq = k8 * 4;
  int swz = k8 << 3;        // column swizzle for these positions (pos>>2 == k8)
  float s0 = 0.f, s1 = 0.f, s2 = 0.f, s3 = 0.f;
  float q0 = 0.f, q1 = 0.f, q2 = 0.f, q3 = 0.f;
  #pragma unroll
  for (int it = 0; it < 8; ++it) {
    int c = it * 32 + g;
    size_t ga = base + (size_t)c * N_ + xq;
    float4 v4 = *(const float4*)&vi[ga];
    float4 i4 = *(const float4*)&ir[ga];
    float4 sv;
    sv.x = v4.x - i4.x; sv.y = v4.y - i4.y; sv.z = v4.z - i4.z; sv.w = v4.w - i4.w;
    ushort4 sb, vb;
    sb.x = f2bf(sv.x); sb.y = f2bf(sv.y); sb.z = f2bf(sv.z); sb.w = f2bf(sv.w);
    vb.x = f2bf(v4.x); vb.y = f2bf(v4.y); vb.z = f2bf(v4.z); vb.w = f2bf(v4.w);
    *(ushort4*)&subB[ga] = sb;
    *(ushort4*)&viB[ga] = vb;
    int cs = c ^ swz;
    tile[(xq + 0) * 256 + cs] = sb.x;
    tile[(xq + 1) * 256 + cs] = sb.y;
    tile[(xq + 2) * 256 + cs] = sb.z;
    tile[(xq + 3) * 256 + cs] = sb.w;
    s0 += sv.x; q0 += sv.x * sv.x;
    s1 += sv.y; q1 += sv.y * sv.y;
    s2 += sv.z; q2 += sv.z * sv.z;
    s3 += sv.w; q3 += sv.w * sv.w;
  }
  // reduce over the 8 in-wave channel subgroups (lanes differing in bits 3..5)
  #pragma unroll
  for (int m = 8; m <= 32; m <<= 1) {
    s0 += __shfl_xor(s0, m); q0 += __shfl_xor(q0, m);
    s1 += __shfl_xor(s1, m); q1 += __shfl_xor(q1, m);
    s2 += __shfl_xor(s2, m); q2 += __shfl_xor(q2, m);
    s3 += __shfl_xor(s3, m); q3 += __shfl_xor(q3, m);
  }
  int w = t >> 6, lt = t & 63;
  if ((lt >> 3) == 0) {    // one lane per (wave, position-quad)
    redS[w][xq + 0] = s0; redS2[w][xq + 0] = q0;
    redS[w][xq + 1] = s1; redS2[w][xq + 1] = q1;
    redS[w][xq + 2] = s2; redS2[w][xq + 2] = q2;
    redS[w][xq + 3] = s3; redS2[w][xq + 3] = q3;
  }
  __syncthreads();
  if (t < 32) {
    float s = redS[0][t] + redS[1][t] + redS[2][t] + redS[3][t];
    float ss = redS2[0][t] + redS2[1][t] + redS2[2][t] + redS2[3][t];
    float mu = s * (1.f / 256.f);
    float var = ss * (1.f / 256.f) - mu * mu;
    meanS[t] = mu;
    rstdS[t] = rsqrtf(var + EPS_);
  }
  __syncthreads();
  int pos = t >> 3;
  float mu = meanS[pos], rs = rstdS[pos];
  int swzr = (pos >> 2) & 7;
  size_t xrow = ((size_t)b * N_ + (size_t)y * 64 + half * 32 + pos) * 256;
  #pragma unroll
  for (int j = 0; j < 4; ++j) {
    int ci = (t & 7) + 8 * j;
    u16x8 tv = *(const u16x8*)&tile[pos * 256 + ((ci ^ swzr) * 8)];
    int c0 = ci * 8;
    u16x8 ov;
    #pragma unroll
    for (int e = 0; e < 8; ++e) {
      float v = bf2f((unsigned short)tv[e]);
      ov[e] = f2bf((v - mu) * rs * sG[c0 + e] + sB[c0 + e]);
    }
    *(u16x8*)&xn[xrow + c0] = ov;
  }
}

// ---------------- MFMA GEMM: C[M,N] = A[M,256] * B[N,256]^T ----------------
// Flat grid, XCD-aware swizzle: blocks sharing one A m-tile land on one XCD
// (flat%8 = XCD on MI355X round-robin dispatch) -> A re-reads hit L2.
// NT = number of 128-wide n-tiles (6 for qkv, 2 for proj).
template<int EPI, int NT>
__global__ __launch_bounds__(256) void k_gemm_mfma(
    const unsigned short* __restrict__ A,
    const unsigned short* __restrict__ Bw,
    unsigned short* __restrict__ Cout,
    const float* __restrict__ bias,
    const unsigned short* __restrict__ subB,
    int ldc)
{
  __shared__ __align__(16) unsigned short As[128 * 32];
  __shared__ __align__(16) unsigned short Bs[128 * 32];
  __shared__ __align__(16) unsigned short Cs[64 * 136];
  int flat = blockIdx.x;
  int xcd = flat & 7;
  int l = flat >> 3;
  int ml = l / NT;
  int nn = l - ml * NT;
  int m0 = (xcd * 32 + ml) * 128;
  int n0 = nn * 128;
  int tid = threadIdx.x;
  int wv = tid >> 6;
  int lane = tid & 63;
  int mw = (wv >> 1) * 64, nw = (wv & 1) * 64;
  int r = lane & 15, q = lane >> 4;

  int seg0 = wv * 2;
  int srow0 = seg0 * 16 + (lane >> 2);
  int scol = (lane & 3) * 8;
  const unsigned short* ga0 = A  + (size_t)(m0 + srow0) * 256 + scol;
  const unsigned short* ga1 = ga0 + 16 * 256;
  const unsigned short* gb0 = Bw + (size_t)(n0 + srow0) * 256 + scol;
  const unsigned short* gb1 = gb0 + 16 * 256;
  unsigned short* la0 = &As[seg0 * 512];
  unsigned short* la1 = la0 + 512;
  unsigned short* lb0 = &Bs[seg0 * 512];
  unsigned short* lb1 = lb0 + 512;

  f32x4 acc[4][4];
  #pragma unroll
  for (int i = 0; i < 4; ++i)
    #pragma unroll
    for (int j = 0; j < 4; ++j)
      acc[i][j] = (f32x4){0.f, 0.f, 0.f, 0.f};

  for (int k0 = 0; k0 < 256; k0 += 32) {
    GLD_LDS16(ga0 + k0, la0);
    GLD_LDS16(ga1 + k0, la1);
    GLD_LDS16(gb0 + k0, lb0);
    GLD_LDS16(gb1 + k0, lb1);
    __syncthreads();
    bf16x8 af[4], bfr[4];
    #pragma unroll
    for (int mt = 0; mt < 4; ++mt)
      af[mt] = *(const bf16x8*)&As[(mw + mt * 16 + r) * 32 + q * 8];
    #pragma unroll
    for (int nt = 0; nt < 4; ++nt)
      bfr[nt] = *(const bf16x8*)&Bs[(nw + nt * 16 + r) * 32 + q * 8];
    #pragma unroll
    for (int mt = 0; mt < 4; ++mt)
      #pragma unroll
      for (int nt = 0; nt < 4; ++nt)
        acc[mt][nt] = __builtin_amdgcn_mfma_f32_16x16x32_bf16(af[mt], bfr[nt], acc[mt][nt], 0, 0, 0);
    __syncthreads();
  }

  int b = m0 >> 12;
  int nn0 = m0 & 4095;
  #pragma unroll
  for (int pass = 0; pass < 2; ++pass) {
    __syncthreads();
    if (EPI == 0) {
      if ((wv >> 1) == pass) {
        #pragma unroll
        for (int mt = 0; mt < 4; ++mt) {
          int lr = mt * 16 + q * 4;
          #pragma unroll
          for (int nt = 0; nt < 4; ++nt) {
            int col = nw + nt * 16 + r;
            #pragma unroll
            for (int rr = 0; rr < 4; ++rr)
              Cs[(lr + rr) * 136 + col] = f2bf(acc[mt][nt][rr]);
          }
        }
      }
    } else {
      if ((wv & 1) == pass) {
        #pragma unroll
        for (int nt = 0; nt < 4; ++nt) {
          int lr = nt * 16 + r;
          #pragma unroll
          for (int mt = 0; mt < 4; ++mt) {
            int pc = mw + mt * 16 + q * 4;
            #pragma unroll
            for (int rr = 0; rr < 4; ++rr)
              Cs[lr * 136 + pc + rr] = f2bf(acc[mt][nt][rr]);
          }
        }
      }
    }
    __syncthreads();
    if (EPI == 0) {
      #pragma unroll
      for (int cc = 0; cc < 4; ++cc) {
        int ch = cc * 256 + tid;
        int row = ch >> 4, cg = ch & 15;
        u16x8 cv = *(const u16x8*)&Cs[row * 136 + cg * 8];
        int m = m0 + pass * 64 + row;
        *(u16x8*)&Cout[(size_t)m * ldc + n0 + cg * 8] = cv;
      }
    } else {
      #pragma unroll
      for (int cc = 0; cc < 4; ++cc) {
        int ch = cc * 256 + tid;
        int row = ch >> 4, cg = ch & 15;
        u16x8 cv = *(const u16x8*)&Cs[row * 136 + cg * 8];
        int c = n0 + pass * 64 + row;
        size_t idx = ((size_t)(b * 256 + c)) * 4096 + nn0 + cg * 8;
        u16x8 sv = *(const u16x8*)&subB[idx];
        float bb = bias[c];
        u16x8 ov;
        #pragma unroll
        for (int e = 0; e < 8; ++e)
          ov[e] = f2bf(bf2f((unsigned short)cv[e]) + bb + bf2f((unsigned short)sv[e]));
        *(u16x8*)&Cout[idx] = ov;
      }
    }
  }
}

// ---------------- kernel 3: dilated local attention ----------------
__global__ __launch_bounds__(256) void k_attn(
    const unsigned short* __restrict__ qkv,   // [NPOS, 768] bf16
    unsigned short* __restrict__ y)           // [NPOS, 256] bf16
{
  int t = threadIdx.x;
  int sub = t >> 2;
  int lane4 = t & 3;
  int item = blockIdx.x * 64 + sub;
  int ih = item & 7;
  int p = item >> 3;
  int i = ih >> 1, h = ih & 1;
  int dil = i + 1;
  int b = p >> 12;
  int n = p & 4095;
  int py = n >> 6, px = n & 63;
  int off = i * 64 + h * 32 + lane4 * 8;
  const unsigned short* base = qkv + off;

  uint4 qw = *(const uint4*)(base + (size_t)p * 768);
  float q0 = blo(qw.x), q1 = bhi(qw.x), q2 = blo(qw.y), q3 = bhi(qw.y),
        q4 = blo(qw.z), q5 = bhi(qw.z), q6 = blo(qw.w), q7 = bhi(qw.w);

  int pj[9];
  #pragma unroll
  for (int j = 0; j < 9; ++j) {
    int ny = py + (j / 3 - 1) * dil;
    int nx = px + (j % 3 - 1) * dil;
    bool ok = ((unsigned)ny < 64u) && ((unsigned)nx < 64u);
    pj[j] = ok ? ((b << 12) + (ny << 6) + nx) : -1;
  }

  float sc[9];
  #pragma unroll
  for (int j = 0; j < 9; ++j) {
    float s = 0.f;
    if (pj[j] >= 0) {
      uint4 kw = *(const uint4*)(base + 256 + (size_t)pj[j] * 768);
      s  = q0 * blo(kw.x) + q1 * bhi(kw.x);
      s += q2 * blo(kw.y) + q3 * bhi(kw.y);
      s += q4 * blo(kw.z) + q5 * bhi(kw.z);
      s += q6 * blo(kw.w) + q7 * bhi(kw.w);
    }
    s += __shfl_xor(s, 1, 4);
    s += __shfl_xor(s, 2, 4);
    sc[j] = s * SCALE_;             // zero-pad taps -> score exactly 0
  }

  float mx = sc[0];
  #pragma unroll
  for (int j = 1; j < 9; ++j) mx = fmaxf(mx, sc[j]);
  float e[9], ssum = 0.f;
  #pragma unroll
  for (int j = 0; j < 9; ++j) { e[j] = __expf(sc[j] - mx); ssum += e[j]; }
  float inv = 1.f / ssum;

  float o0 = 0.f, o1 = 0.f, o2 = 0.f, o3 = 0.f, o4 = 0.f, o5 = 0.f, o6 = 0.f, o7 = 0.f;
  #pragma unroll
  for (int j = 0; j < 9; ++j) {
    if (pj[j] >= 0) {
      float w = e[j] * inv;
      uint4 vw = *(const uint4*)(base + 512 + (size_t)pj[j] * 768);
      o0 += w * blo(vw.x); o1 += w * bhi(vw.x);
      o2 += w * blo(vw.y); o3 += w * bhi(vw.y);
      o4 += w * blo(vw.z); o5 += w * bhi(vw.z);
      o6 += w * blo(vw.w); o7 += w * bhi(vw.w);
    }
  }

  u16x8 ov;
  ov[0] = f2bf(o0); ov[1] = f2bf(o1); ov[2] = f2bf(o2); ov[3] = f2bf(o3);
  ov[4] = f2bf(o4); ov[5] = f2bf(o5); ov[6] = f2bf(o6); ov[7] = f2bf(o7);
  *(u16x8*)(y + (size_t)p * 256 + off) = ov;
}

// ---------------- kernel 5: per-(b,c) 64x64x64 MFMA matmul, dup output ----
// o[i,j] = sum_k vi[i,k] * div[k,j]; A=Vs row-major, B=Ds transposed [j][k].
// Row stride 72 ushorts = 144 B = 9x16B: b128-aligned, conflict-free frags.
__global__ __launch_bounds__(256) void k_bmm(
    const unsigned short* __restrict__ viB,
    const unsigned short* __restrict__ divmB,
    float* __restrict__ out)
{
  __shared__ __align__(16) unsigned short Vs[64 * 72];
  __shared__ __align__(16) unsigned short Ds[64 * 72];
  int bc = blockIdx.x;
  size_t base = (size_t)bc * 4096;
  int t = threadIdx.x;
  {
    int flat = t * 16;
    int row = flat >> 6, col = flat & 63;   // row: i for vi / k for div
    u16x8 v0 = *(const u16x8*)&viB[base + flat];
    u16x8 v1 = *(const u16x8*)&viB[base + flat + 8];
    *(u16x8*)&Vs[row * 72 + col] = v0;
    *(u16x8*)&Vs[row * 72 + col + 8] = v1;
    u16x8 d0 = *(const u16x8*)&divmB[base + flat];
    u16x8 d1 = *(const u16x8*)&divmB[base + flat + 8];
    #pragma unroll
    for (int e = 0; e < 8; ++e) {
      Ds[(col + e) * 72 + row] = (unsigned short)d0[e];       // Ds[j][k]
      Ds[(col + 8 + e) * 72 + row] = (unsigned short)d1[e];
    }
  }
  __syncthreads();
  int w = t >> 6, lane = t & 63;
  int r = lane & 15, q = lane >> 4;
  int wi = (w >> 1) * 32, wj = (w & 1) * 32;
  f32x4 acc[2][2];
  #pragma unroll
  for (int i = 0; i < 2; ++i)
    #pragma unroll
    for (int j = 0; j < 2; ++j)
      acc[i][j] = (f32x4){0.f, 0.f, 0.f, 0.f};
  #pragma unroll
  for (int ks = 0; ks < 2; ++ks) {
    bf16x8 a[2], bfr[2];
    #pragma unroll
    for (int ti = 0; ti < 2; ++ti)
      a[ti] = *(const bf16x8*)&Vs[(wi + ti * 16 + r) * 72 + ks * 32 + q * 8];
    #pragma unroll
    for (int tj = 0; tj < 2; ++tj)
      bfr[tj] = *(const bf16x8*)&Ds[(wj + tj * 16 + r) * 72 + ks * 32 + q * 8];
    #pragma unroll
    for (int ti = 0; ti < 2; ++ti)
      #pragma unroll
      for (int tj = 0; tj < 2; ++tj)
        acc[ti][tj] = __builtin_amdgcn_mfma_f32_16x16x32_bf16(a[ti], bfr[tj], acc[ti][tj], 0, 0, 0);
  }
  #pragma unroll
  for (int ti = 0; ti < 2; ++ti)
    #pragma unroll
    for (int tj = 0; tj < 2; ++tj)
      #pragma unroll
      for (int rr = 0; rr < 4; ++rr) {
        int row = wi + ti * 16 + q * 4 + rr;
        int col = wj + tj * 16 + r;
        float v = acc[ti][tj][rr];
        out[base + row * 64 + col] = v;
        out[8388608ull + base + row * 64 + col] = v;
      }
}

extern "C" void kernel_launch(void* const* d_in, const int* in_sizes, int n_in,
                              void* d_out, int out_size, void* d_ws, size_t ws_size,
                              hipStream_t stream) {
  const float* vi     = (const float*)d_in[0];
  const float* ir     = (const float*)d_in[1];
  const float* w_qkv  = (const float*)d_in[2];
  const float* proj_w = (const float*)d_in[3];
  const float* proj_b = (const float*)d_in[4];
  const float* ln_g   = (const float*)d_in[5];
  const float* ln_b   = (const float*)d_in[6];
  float* out = (float*)d_out;
  char* ws = (char*)d_ws;
  unsigned short* subB = (unsigned short*)(ws);                // 16.8 MB BCHW bf16
  unsigned short* qkvb = (unsigned short*)(ws + 16777216);     // 50.3 MB [NPOS,768]
  unsigned short* divmB= (unsigned short*)(ws + 16777216);     // reuse, 16.8 MB BCHW
  unsigned short* xnb  = (unsigned short*)(ws + 67108864);     // 16.8 MB [NPOS,256]
  unsigned short* yb   = (unsigned short*)(ws + 83886080);     // 16.8 MB [NPOS,256]
  unsigned short* viB  = (unsigned short*)(ws + 100663296);    // 16.8 MB BCHW bf16
  unsigned short* wqb  = (unsigned short*)(ws + 117440512);    // [768,256] bf16
  unsigned short* pwb  = wqb + 196608;                         // [256,256] bf16

  k_pre<<<1280, 256, 0, stream>>>(vi, ir, w_qkv, proj_w, ln_g, ln_b, wqb, subB, viB, xnb);
  k_gemm_mfma<0, 6><<<1536, 256, 0, stream>>>(xnb, wqb, qkvb, nullptr, nullptr, 768);
  k_attn<<<4096, 256, 0, stream>>>(qkvb, yb);
  k_gemm_mfma<1, 2><<<512, 256, 0, stream>>>(yb, pwb, divmB, proj_b, subB, 0);
  k_bmm<<<2048, 256, 0, stream>>>(viB, divmB, out);
}

// Round 2
// 212.076 us; speedup vs baseline: 1.0372x; 1.0372x over previous
//
#include <hip/hip_runtime.h>
#include <math.h>

#define B_ 8
#define C_ 256
#define N_ 4096          // H*W
#define NPOS 32768       // B*N
#define SCALE_ 0.1767766952966369f
#define EPS_ 1e-5f

typedef __attribute__((ext_vector_type(8))) short bf16x8;
typedef __attribute__((ext_vector_type(8))) unsigned short u16x8;
typedef __attribute__((ext_vector_type(4))) float f32x4;

__device__ __forceinline__ unsigned short f2bf(float f) {
  union { float f; unsigned u; } v; v.f = f;
  unsigned r = v.u + 0x7fff + ((v.u >> 16) & 1);   // RNE
  return (unsigned short)(r >> 16);
}
__device__ __forceinline__ float bf2f(unsigned short u) {
  union { unsigned u; float f; } v; v.u = ((unsigned)u) << 16; return v.f;
}
__device__ __forceinline__ float blo(unsigned u) {
  union { unsigned u; float f; } v; v.u = u << 16; return v.f;
}
__device__ __forceinline__ float bhi(unsigned u) {
  union { unsigned u; float f; } v; v.u = u & 0xffff0000u; return v.f;
}

#define GLD_LDS16(g, l) \
  __builtin_amdgcn_global_load_lds((const __attribute__((address_space(1))) unsigned int*)(g), \
                                   (__attribute__((address_space(3))) unsigned int*)(l), 16, 0, 0)

// ---- kernel 1: [blocks 0..255] weight cvt  [blocks 256..1279] sub+LN ----
// sub_ln: writes subB bf16 (BCHW), viB bf16 (BCHW), xn bf16 [NPOS,256]
// v3: v2 structure (16KB bf16 tile, shfl reduce, 16B xn stores) but
// __launch_bounds__(256,4): VGPR budget 128 (v2's (256,8) forced 32 VGPR ->
// 13 regs spilled to scratch = +21MB HBM traffic, loads serialized).
// Load phase issues all 16 float4 loads into regs before any store: 16
// outstanding 16B/lane loads x 16 waves/CU hides HBM latency.
__global__ __launch_bounds__(256, 4) void k_pre(
    const float* __restrict__ vi, const float* __restrict__ ir,
    const float* __restrict__ wq, const float* __restrict__ pw,
    const float* __restrict__ ln_g, const float* __restrict__ ln_b,
    unsigned short* __restrict__ wdst,
    unsigned short* __restrict__ subB, unsigned short* __restrict__ viB,
    unsigned short* __restrict__ xn)
{
  __shared__ __align__(16) unsigned short tile[32 * 256];   // [pos][c ^ ((pos>>2)<<3)]
  __shared__ float redS[4][32], redS2[4][32];
  __shared__ float meanS[32], rstdS[32];
  __shared__ float sG[256], sB[256];
  int t = threadIdx.x;
  if (blockIdx.x < 256) {
    int i4 = blockIdx.x * 256 + t;   // 65536 float4s
    float4 v = (i4 < 49152) ? ((const float4*)wq)[i4] : ((const float4*)pw)[i4 - 49152];
    ushort4 o;
    o.x = f2bf(v.x); o.y = f2bf(v.y); o.z = f2bf(v.z); o.w = f2bf(v.w);
    ((ushort4*)wdst)[i4] = o;
    return;
  }
  int blk = blockIdx.x - 256;              // b*128 + y*2 + half
  int b = blk >> 7;
  int y = (blk >> 1) & 63;
  int half = blk & 1;
  size_t base = (size_t)b * C_ * N_ + (size_t)y * 64 + half * 32;
  sG[t] = ln_g[t];
  sB[t] = ln_b[t];
  int g = t >> 3;           // channel subgroup (in-wave bits 0..2 + wave*8)
  int k8 = t & 7;           // position quad index: positions k8*4 .. k8*4+3
  int xq = k8 * 4;
  int swz = k8 << 3;        // column swizzle for these positions (pos>>2 == k8)

  // ---- phase 1: issue ALL loads first (max MLP), then compute/stores ----
  float4 V[8], I[8];
  #pragma unroll
  for (int it = 0; it < 8; ++it) {
    size_t ga = base + (size_t)(it * 32 + g) * N_ + xq;
    V[it] = *(const float4*)&vi[ga];
  }
  #pragma unroll
  for (int it = 0; it < 8; ++it) {
    size_t ga = base + (size_t)(it * 32 + g) * N_ + xq;
    I[it] = *(const float4*)&ir[ga];
  }

  float s0 = 0.f, s1 = 0.f, s2 = 0.f, s3 = 0.f;
  float q0 = 0.f, q1 = 0.f, q2 = 0.f, q3 = 0.f;
  #pragma unroll
  for (int it = 0; it < 8; ++it) {
    int c = it * 32 + g;
    size_t ga = base + (size_t)c * N_ + xq;
    float4 v4 = V[it];
    float4 i4 = I[it];
    float4 sv;
    sv.x = v4.x - i4.x; sv.y = v4.y - i4.y; sv.z = v4.z - i4.z; sv.w = v4.w - i4.w;
    ushort4 sb, vb;
    sb.x = f2bf(sv.x); sb.y = f2bf(sv.y); sb.z = f2bf(sv.z); sb.w = f2bf(sv.w);
    vb.x = f2bf(v4.x); vb.y = f2bf(v4.y); vb.z = f2bf(v4.z); vb.w = f2bf(v4.w);
    *(ushort4*)&subB[ga] = sb;
    *(ushort4*)&viB[ga] = vb;
    int cs = c ^ swz;
    tile[(xq + 0) * 256 + cs] = sb.x;
    tile[(xq + 1) * 256 + cs] = sb.y;
    tile[(xq + 2) * 256 + cs] = sb.z;
    tile[(xq + 3) * 256 + cs] = sb.w;
    s0 += sv.x; q0 += sv.x * sv.x;
    s1 += sv.y; q1 += sv.y * sv.y;
    s2 += sv.z; q2 += sv.z * sv.z;
    s3 += sv.w; q3 += sv.w * sv.w;
  }
  // reduce over the 8 in-wave channel subgroups (lanes differing in bits 3..5)
  #pragma unroll
  for (int m = 8; m <= 32; m <<= 1) {
    s0 += __shfl_xor(s0, m); q0 += __shfl_xor(q0, m);
    s1 += __shfl_xor(s1, m); q1 += __shfl_xor(q1, m);
    s2 += __shfl_xor(s2, m); q2 += __shfl_xor(q2, m);
    s3 += __shfl_xor(s3, m); q3 += __shfl_xor(q3, m);
  }
  int w = t >> 6, lt = t & 63;
  if ((lt >> 3) == 0) {    // one lane per (wave, position-quad)
    redS[w][xq + 0] = s0; redS2[w][xq + 0] = q0;
    redS[w][xq + 1] = s1; redS2[w][xq + 1] = q1;
    redS[w][xq + 2] = s2; redS2[w][xq + 2] = q2;
    redS[w][xq + 3] = s3; redS2[w][xq + 3] = q3;
  }
  __syncthreads();
  if (t < 32) {
    float s = redS[0][t] + redS[1][t] + redS[2][t] + redS[3][t];
    float ss = redS2[0][t] + redS2[1][t] + redS2[2][t] + redS2[3][t];
    float mu = s * (1.f / 256.f);
    float var = ss * (1.f / 256.f) - mu * mu;
    meanS[t] = mu;
    rstdS[t] = rsqrtf(var + EPS_);
  }
  __syncthreads();
  int pos = t >> 3;
  float mu = meanS[pos], rs = rstdS[pos];
  int swzr = (pos >> 2) & 7;
  size_t xrow = ((size_t)b * N_ + (size_t)y * 64 + half * 32 + pos) * 256;
  #pragma unroll
  for (int j = 0; j < 4; ++j) {
    int ci = (t & 7) + 8 * j;
    u16x8 tv = *(const u16x8*)&tile[pos * 256 + ((ci ^ swzr) * 8)];
    int c0 = ci * 8;
    u16x8 ov;
    #pragma unroll
    for (int e = 0; e < 8; ++e) {
      float v = bf2f((unsigned short)tv[e]);
      ov[e] = f2bf((v - mu) * rs * sG[c0 + e] + sB[c0 + e]);
    }
    *(u16x8*)&xn[xrow + c0] = ov;
  }
}

// ---------------- MFMA GEMM: C[M,N] = A[M,256] * B[N,256]^T ----------------
// Flat grid, XCD-aware swizzle: blocks sharing one A m-tile land on one XCD
// (flat%8 = XCD on MI355X round-robin dispatch) -> A re-reads hit L2.
// NT = number of 128-wide n-tiles (6 for qkv, 2 for proj).
template<int EPI, int NT>
__global__ __launch_bounds__(256) void k_gemm_mfma(
    const unsigned short* __restrict__ A,
    const unsigned short* __restrict__ Bw,
    unsigned short* __restrict__ Cout,
    const float* __restrict__ bias,
    const unsigned short* __restrict__ subB,
    int ldc)
{
  __shared__ __align__(16) unsigned short As[128 * 32];
  __shared__ __align__(16) unsigned short Bs[128 * 32];
  __shared__ __align__(16) unsigned short Cs[64 * 136];
  int flat = blockIdx.x;
  int xcd = flat & 7;
  int l = flat >> 3;
  int ml = l / NT;
  int nn = l - ml * NT;
  int m0 = (xcd * 32 + ml) * 128;
  int n0 = nn * 128;
  int tid = threadIdx.x;
  int wv = tid >> 6;
  int lane = tid & 63;
  int mw = (wv >> 1) * 64, nw = (wv & 1) * 64;
  int r = lane & 15, q = lane >> 4;

  int seg0 = wv * 2;
  int srow0 = seg0 * 16 + (lane >> 2);
  int scol = (lane & 3) * 8;
  const unsigned short* ga0 = A  + (size_t)(m0 + srow0) * 256 + scol;
  const unsigned short* ga1 = ga0 + 16 * 256;
  const unsigned short* gb0 = Bw + (size_t)(n0 + srow0) * 256 + scol;
  const unsigned short* gb1 = gb0 + 16 * 256;
  unsigned short* la0 = &As[seg0 * 512];
  unsigned short* la1 = la0 + 512;
  unsigned short* lb0 = &Bs[seg0 * 512];
  unsigned short* lb1 = lb0 + 512;

  f32x4 acc[4][4];
  #pragma unroll
  for (int i = 0; i < 4; ++i)
    #pragma unroll
    for (int j = 0; j < 4; ++j)
      acc[i][j] = (f32x4){0.f, 0.f, 0.f, 0.f};

  for (int k0 = 0; k0 < 256; k0 += 32) {
    GLD_LDS16(ga0 + k0, la0);
    GLD_LDS16(ga1 + k0, la1);
    GLD_LDS16(gb0 + k0, lb0);
    GLD_LDS16(gb1 + k0, lb1);
    __syncthreads();
    bf16x8 af[4], bfr[4];
    #pragma unroll
    for (int mt = 0; mt < 4; ++mt)
      af[mt] = *(const bf16x8*)&As[(mw + mt * 16 + r) * 32 + q * 8];
    #pragma unroll
    for (int nt = 0; nt < 4; ++nt)
      bfr[nt] = *(const bf16x8*)&Bs[(nw + nt * 16 + r) * 32 + q * 8];
    #pragma unroll
    for (int mt = 0; mt < 4; ++mt)
      #pragma unroll
      for (int nt = 0; nt < 4; ++nt)
        acc[mt][nt] = __builtin_amdgcn_mfma_f32_16x16x32_bf16(af[mt], bfr[nt], acc[mt][nt], 0, 0, 0);
    __syncthreads();
  }

  int b = m0 >> 12;
  int nn0 = m0 & 4095;
  #pragma unroll
  for (int pass = 0; pass < 2; ++pass) {
    __syncthreads();
    if (EPI == 0) {
      if ((wv >> 1) == pass) {
        #pragma unroll
        for (int mt = 0; mt < 4; ++mt) {
          int lr = mt * 16 + q * 4;
          #pragma unroll
          for (int nt = 0; nt < 4; ++nt) {
            int col = nw + nt * 16 + r;
            #pragma unroll
            for (int rr = 0; rr < 4; ++rr)
              Cs[(lr + rr) * 136 + col] = f2bf(acc[mt][nt][rr]);
          }
        }
      }
    } else {
      if ((wv & 1) == pass) {
        #pragma unroll
        for (int nt = 0; nt < 4; ++nt) {
          int lr = nt * 16 + r;
          #pragma unroll
          for (int mt = 0; mt < 4; ++mt) {
            int pc = mw + mt * 16 + q * 4;
            #pragma unroll
            for (int rr = 0; rr < 4; ++rr)
              Cs[lr * 136 + pc + rr] = f2bf(acc[mt][nt][rr]);
          }
        }
      }
    }
    __syncthreads();
    if (EPI == 0) {
      #pragma unroll
      for (int cc = 0; cc < 4; ++cc) {
        int ch = cc * 256 + tid;
        int row = ch >> 4, cg = ch & 15;
        u16x8 cv = *(const u16x8*)&Cs[row * 136 + cg * 8];
        int m = m0 + pass * 64 + row;
        *(u16x8*)&Cout[(size_t)m * ldc + n0 + cg * 8] = cv;
      }
    } else {
      #pragma unroll
      for (int cc = 0; cc < 4; ++cc) {
        int ch = cc * 256 + tid;
        int row = ch >> 4, cg = ch & 15;
        u16x8 cv = *(const u16x8*)&Cs[row * 136 + cg * 8];
        int c = n0 + pass * 64 + row;
        size_t idx = ((size_t)(b * 256 + c)) * 4096 + nn0 + cg * 8;
        u16x8 sv = *(const u16x8*)&subB[idx];
        float bb = bias[c];
        u16x8 ov;
        #pragma unroll
        for (int e = 0; e < 8; ++e)
          ov[e] = f2bf(bf2f((unsigned short)cv[e]) + bb + bf2f((unsigned short)sv[e]));
        *(u16x8*)&Cout[idx] = ov;
      }
    }
  }
}

// ---------------- kernel 3: dilated local attention ----------------
__global__ __launch_bounds__(256) void k_attn(
    const unsigned short* __restrict__ qkv,   // [NPOS, 768] bf16
    unsigned short* __restrict__ y)           // [NPOS, 256] bf16
{
  int t = threadIdx.x;
  int sub = t >> 2;
  int lane4 = t & 3;
  int item = blockIdx.x * 64 + sub;
  int ih = item & 7;
  int p = item >> 3;
  int i = ih >> 1, h = ih & 1;
  int dil = i + 1;
  int b = p >> 12;
  int n = p & 4095;
  int py = n >> 6, px = n & 63;
  int off = i * 64 + h * 32 + lane4 * 8;
  const unsigned short* base = qkv + off;

  uint4 qw = *(const uint4*)(base + (size_t)p * 768);
  float q0 = blo(qw.x), q1 = bhi(qw.x), q2 = blo(qw.y), q3 = bhi(qw.y),
        q4 = blo(qw.z), q5 = bhi(qw.z), q6 = blo(qw.w), q7 = bhi(qw.w);

  int pj[9];
  #pragma unroll
  for (int j = 0; j < 9; ++j) {
    int ny = py + (j / 3 - 1) * dil;
    int nx = px + (j % 3 - 1) * dil;
    bool ok = ((unsigned)ny < 64u) && ((unsigned)nx < 64u);
    pj[j] = ok ? ((b << 12) + (ny << 6) + nx) : -1;
  }

  float sc[9];
  #pragma unroll
  for (int j = 0; j < 9; ++j) {
    float s = 0.f;
    if (pj[j] >= 0) {
      uint4 kw = *(const uint4*)(base + 256 + (size_t)pj[j] * 768);
      s  = q0 * blo(kw.x) + q1 * bhi(kw.x);
      s += q2 * blo(kw.y) + q3 * bhi(kw.y);
      s += q4 * blo(kw.z) + q5 * bhi(kw.z);
      s += q6 * blo(kw.w) + q7 * bhi(kw.w);
    }
    s += __shfl_xor(s, 1, 4);
    s += __shfl_xor(s, 2, 4);
    sc[j] = s * SCALE_;             // zero-pad taps -> score exactly 0
  }

  float mx = sc[0];
  #pragma unroll
  for (int j = 1; j < 9; ++j) mx = fmaxf(mx, sc[j]);
  float e[9], ssum = 0.f;
  #pragma unroll
  for (int j = 0; j < 9; ++j) { e[j] = __expf(sc[j] - mx); ssum += e[j]; }
  float inv = 1.f / ssum;

  float o0 = 0.f, o1 = 0.f, o2 = 0.f, o3 = 0.f, o4 = 0.f, o5 = 0.f, o6 = 0.f, o7 = 0.f;
  #pragma unroll
  for (int j = 0; j < 9; ++j) {
    if (pj[j] >= 0) {
      float w = e[j] * inv;
      uint4 vw = *(const uint4*)(base + 512 + (size_t)pj[j] * 768);
      o0 += w * blo(vw.x); o1 += w * bhi(vw.x);
      o2 += w * blo(vw.y); o3 += w * bhi(vw.y);
      o4 += w * blo(vw.z); o5 += w * bhi(vw.z);
      o6 += w * blo(vw.w); o7 += w * bhi(vw.w);
    }
  }

  u16x8 ov;
  ov[0] = f2bf(o0); ov[1] = f2bf(o1); ov[2] = f2bf(o2); ov[3] = f2bf(o3);
  ov[4] = f2bf(o4); ov[5] = f2bf(o5); ov[6] = f2bf(o6); ov[7] = f2bf(o7);
  *(u16x8*)(y + (size_t)p * 256 + off) = ov;
}

// ---------------- kernel 5: per-(b,c) 64x64x64 MFMA matmul, dup output ----
// o[i,j] = sum_k vi[i,k] * div[k,j]; A=Vs row-major, B=Ds transposed [j][k].
// Row stride 72 ushorts = 144 B = 9x16B: b128-aligned, conflict-free frags.
__global__ __launch_bounds__(256) void k_bmm(
    const unsigned short* __restrict__ viB,
    const unsigned short* __restrict__ divmB,
    float* __restrict__ out)
{
  __shared__ __align__(16) unsigned short Vs[64 * 72];
  __shared__ __align__(16) unsigned short Ds[64 * 72];
  int bc = blockIdx.x;
  size_t base = (size_t)bc * 4096;
  int t = threadIdx.x;
  {
    int flat = t * 16;
    int row = flat >> 6, col = flat & 63;   // row: i for vi / k for div
    u16x8 v0 = *(const u16x8*)&viB[base + flat];
    u16x8 v1 = *(const u16x8*)&viB[base + flat + 8];
    *(u16x8*)&Vs[row * 72 + col] = v0;
    *(u16x8*)&Vs[row * 72 + col + 8] = v1;
    u16x8 d0 = *(const u16x8*)&divmB[base + flat];
    u16x8 d1 = *(const u16x8*)&divmB[base + flat + 8];
    #pragma unroll
    for (int e = 0; e < 8; ++e) {
      Ds[(col + e) * 72 + row] = (unsigned short)d0[e];       // Ds[j][k]
      Ds[(col + 8 + e) * 72 + row] = (unsigned short)d1[e];
    }
  }
  __syncthreads();
  int w = t >> 6, lane = t & 63;
  int r = lane & 15, q = lane >> 4;
  int wi = (w >> 1) * 32, wj = (w & 1) * 32;
  f32x4 acc[2][2];
  #pragma unroll
  for (int i = 0; i < 2; ++i)
    #pragma unroll
    for (int j = 0; j < 2; ++j)
      acc[i][j] = (f32x4){0.f, 0.f, 0.f, 0.f};
  #pragma unroll
  for (int ks = 0; ks < 2; ++ks) {
    bf16x8 a[2], bfr[2];
    #pragma unroll
    for (int ti = 0; ti < 2; ++ti)
      a[ti] = *(const bf16x8*)&Vs[(wi + ti * 16 + r) * 72 + ks * 32 + q * 8];
    #pragma unroll
    for (int tj = 0; tj < 2; ++tj)
      bfr[tj] = *(const bf16x8*)&Ds[(wj + tj * 16 + r) * 72 + ks * 32 + q * 8];
    #pragma unroll
    for (int ti = 0; ti < 2; ++ti)
      #pragma unroll
      for (int tj = 0; tj < 2; ++tj)
        acc[ti][tj] = __builtin_amdgcn_mfma_f32_16x16x32_bf16(a[ti], bfr[tj], acc[ti][tj], 0, 0, 0);
  }
  #pragma unroll
  for (int ti = 0; ti < 2; ++ti)
    #pragma unroll
    for (int tj = 0; tj < 2; ++tj)
      #pragma unroll
      for (int rr = 0; rr < 4; ++rr) {
        int row = wi + ti * 16 + q * 4 + rr;
        int col = wj + tj * 16 + r;
        float v = acc[ti][tj][rr];
        out[base + row * 64 + col] = v;
        out[8388608ull + base + row * 64 + col] = v;
      }
}

extern "C" void kernel_launch(void* const* d_in, const int* in_sizes, int n_in,
                              void* d_out, int out_size, void* d_ws, size_t ws_size,
                              hipStream_t stream) {
  const float* vi     = (const float*)d_in[0];
  const float* ir     = (const float*)d_in[1];
  const float* w_qkv  = (const float*)d_in[2];
  const float* proj_w = (const float*)d_in[3];
  const float* proj_b = (const float*)d_in[4];
  const float* ln_g   = (const float*)d_in[5];
  const float* ln_b   = (const float*)d_in[6];
  float* out = (float*)d_out;
  char* ws = (char*)d_ws;
  unsigned short* subB = (unsigned short*)(ws);                // 16.8 MB BCHW bf16
  unsigned short* qkvb = (unsigned short*)(ws + 16777216);     // 50.3 MB [NPOS,768]
  unsigned short* divmB= (unsigned short*)(ws + 16777216);     // reuse, 16.8 MB BCHW
  unsigned short* xnb  = (unsigned short*)(ws + 67108864);     // 16.8 MB [NPOS,256]
  unsigned short* yb   = (unsigned short*)(ws + 83886080);     // 16.8 MB [NPOS,256]
  unsigned short* viB  = (unsigned short*)(ws + 100663296);    // 16.8 MB BCHW bf16
  unsigned short* wqb  = (unsigned short*)(ws + 117440512);    // [768,256] bf16
  unsigned short* pwb  = wqb + 196608;                         // [256,256] bf16

  k_pre<<<1280, 256, 0, stream>>>(vi, ir, w_qkv, proj_w, ln_g, ln_b, wqb, subB, viB, xnb);
  k_gemm_mfma<0, 6><<<1536, 256, 0, stream>>>(xnb, wqb, qkvb, nullptr, nullptr, 768);
  k_attn<<<4096, 256, 0, stream>>>(qkvb, yb);
  k_gemm_mfma<1, 2><<<512, 256, 0, stream>>>(yb, pwb, divmB, proj_b, subB, 0);
  k_bmm<<<2048, 256, 0, stream>>>(viB, divmB, out);
}

// Round 3
// 210.880 us; speedup vs baseline: 1.0430x; 1.0057x over previous
//
#include <hip/hip_runtime.h>
#include <math.h>

#define B_ 8
#define C_ 256
#define N_ 4096          // H*W
#define NPOS 32768       // B*N
#define SCALE_ 0.1767766952966369f
#define EPS_ 1e-5f

typedef __attribute__((ext_vector_type(8))) short bf16x8;
typedef __attribute__((ext_vector_type(8))) unsigned short u16x8;
typedef __attribute__((ext_vector_type(4))) float f32x4;

__device__ __forceinline__ unsigned short f2bf(float f) {
  union { float f; unsigned u; } v; v.f = f;
  unsigned r = v.u + 0x7fff + ((v.u >> 16) & 1);   // RNE
  return (unsigned short)(r >> 16);
}
__device__ __forceinline__ float bf2f(unsigned short u) {
  union { unsigned u; float f; } v; v.u = ((unsigned)u) << 16; return v.f;
}
__device__ __forceinline__ float blo(unsigned u) {
  union { unsigned u; float f; } v; v.u = u << 16; return v.f;
}
__device__ __forceinline__ float bhi(unsigned u) {
  union { unsigned u; float f; } v; v.u = u & 0xffff0000u; return v.f;
}

#define GLD_LDS16(g, l) \
  __builtin_amdgcn_global_load_lds((const __attribute__((address_space(1))) unsigned int*)(g), \
                                   (__attribute__((address_space(3))) unsigned int*)(l), 16, 0, 0)

// ---- kernel 1a: pure streaming sub/viB + per-position partial sums ----
// blocks 0..1023: (b, 32-ch chunk, 256-pos group). No transpose, 1 tiny barrier.
// blocks 1024..1279: weight cvt (wq+pw -> bf16).
// partials[chunk][b*4096+pos] = {sum, sumsq} over that chunk's 32 channels.
__global__ __launch_bounds__(256, 4) void k_stream(
    const float* __restrict__ vi, const float* __restrict__ ir,
    const float* __restrict__ wq, const float* __restrict__ pw,
    unsigned short* __restrict__ wdst,
    unsigned short* __restrict__ subB, unsigned short* __restrict__ viB,
    float2* __restrict__ partials)
{
  int t = threadIdx.x;
  int blk = blockIdx.x;
  if (blk >= 1024) {
    int i4 = (blk - 1024) * 256 + t;   // 65536 float4s
    float4 v = (i4 < 49152) ? ((const float4*)wq)[i4] : ((const float4*)pw)[i4 - 49152];
    ushort4 o;
    o.x = f2bf(v.x); o.y = f2bf(v.y); o.z = f2bf(v.z); o.w = f2bf(v.w);
    ((ushort4*)wdst)[i4] = o;
    return;
  }
  __shared__ float redS[4 * 256], redQ[4 * 256];   // [wave][pos-in-block]
  int b = blk >> 7;            // 8
  int chunk = (blk >> 4) & 7;  // 8 chunks of 32 channels
  int pgrp = blk & 15;         // 16 groups of 256 positions
  int posq = t & 63;           // 64 position-quads
  int cg = t >> 6;             // wave id = channel subgroup (8 ch each)
  int c0 = chunk * 32 + cg * 8;
  int n0 = pgrp * 256 + posq * 4;
  size_t base = ((size_t)b * C_ + c0) * N_ + n0;

  // issue all 16 loads first (MLP), then compute + stores
  float4 V[8], I[8];
  #pragma unroll
  for (int j = 0; j < 8; ++j) V[j] = *(const float4*)&vi[base + (size_t)j * N_];
  #pragma unroll
  for (int j = 0; j < 8; ++j) I[j] = *(const float4*)&ir[base + (size_t)j * N_];

  float s0 = 0.f, s1 = 0.f, s2 = 0.f, s3 = 0.f;
  float q0 = 0.f, q1 = 0.f, q2 = 0.f, q3 = 0.f;
  #pragma unroll
  for (int j = 0; j < 8; ++j) {
    float4 v4 = V[j], i4 = I[j];
    float4 sv;
    sv.x = v4.x - i4.x; sv.y = v4.y - i4.y; sv.z = v4.z - i4.z; sv.w = v4.w - i4.w;
    ushort4 sb, vb;
    sb.x = f2bf(sv.x); sb.y = f2bf(sv.y); sb.z = f2bf(sv.z); sb.w = f2bf(sv.w);
    vb.x = f2bf(v4.x); vb.y = f2bf(v4.y); vb.z = f2bf(v4.z); vb.w = f2bf(v4.w);
    *(ushort4*)&subB[base + (size_t)j * N_] = sb;
    *(ushort4*)&viB[base + (size_t)j * N_] = vb;
    s0 += sv.x; q0 += sv.x * sv.x;
    s1 += sv.y; q1 += sv.y * sv.y;
    s2 += sv.z; q2 += sv.z * sv.z;
    s3 += sv.w; q3 += sv.w * sv.w;
  }
  // per-wave partial (8 channels) for 4 positions -> LDS
  *(f32x4*)&redS[cg * 256 + posq * 4] = (f32x4){s0, s1, s2, s3};
  *(f32x4*)&redQ[cg * 256 + posq * 4] = (f32x4){q0, q1, q2, q3};
  __syncthreads();
  // thread t owns block-position t: sum the 4 wave partials, write partials
  float s = redS[t] + redS[256 + t] + redS[512 + t] + redS[768 + t];
  float q = redQ[t] + redQ[256 + t] + redQ[512 + t] + redQ[768 + t];
  partials[(size_t)chunk * NPOS + b * 4096 + pgrp * 256 + t] = make_float2(s, q);
}

// ---- kernel 1b: transpose + LN ----
// block = (b, 64-position tile). Reads subB channel-major (L2/L3-resident),
// swizzled 32KB LDS tile, writes xn [NPOS,256] with full-row coalesced stores.
// Swizzle: tile[pos][c ^ ((pos>>3)<<3)] -> scatter-writes 2-way (free),
// read side recovers channel oct oc of row p at column (oc^(p>>3))*8.
__global__ __launch_bounds__(256, 4) void k_lnt(
    const unsigned short* __restrict__ subB,
    const float2* __restrict__ partials,
    const float* __restrict__ ln_g, const float* __restrict__ ln_b,
    unsigned short* __restrict__ xn)
{
  __shared__ __align__(16) unsigned short tile[64 * 256];  // 32KB
  __shared__ float muS[64], rsS[64];
  __shared__ float sG[256], sBt[256];
  int t = threadIdx.x;
  int blk = blockIdx.x;          // 512: b*64 + pt
  int b = blk >> 6, pt = blk & 63;
  int bp0 = b * 4096 + pt * 64;
  sG[t] = ln_g[t];
  sBt[t] = ln_b[t];
  if (t < 64) {
    float s = 0.f, q = 0.f;
    #pragma unroll
    for (int ch = 0; ch < 8; ++ch) {
      float2 pp = partials[(size_t)ch * NPOS + bp0 + t];
      s += pp.x; q += pp.y;
    }
    float mu = s * (1.f / 256.f);
    float var = q * (1.f / 256.f) - mu * mu;
    muS[t] = mu;
    rsS[t] = rsqrtf(var + EPS_);
  }
  int po = t & 7;        // row-oct: positions po*8..po*8+7
  int c = t >> 3;        // 0..31, +32 per iteration
  // load all 8, then scatter (MLP)
  u16x8 L[8];
  #pragma unroll
  for (int it = 0; it < 8; ++it) {
    int cc = c + it * 32;
    L[it] = *(const u16x8*)&subB[((size_t)b * C_ + cc) * N_ + pt * 64 + po * 8];
  }
  #pragma unroll
  for (int it = 0; it < 8; ++it) {
    int cs = (c + it * 32) ^ (po << 3);
    #pragma unroll
    for (int e = 0; e < 8; ++e)
      tile[(po * 8 + e) * 256 + cs] = (unsigned short)L[it][e];
  }
  __syncthreads();
  // 8 passes: 32 lanes cover one full 512B row (position) each pass
  int pos8 = t >> 5;     // 0..7
  int oc = t & 31;       // channel oct
  #pragma unroll
  for (int pass = 0; pass < 8; ++pass) {
    int p = pass * 8 + pos8;
    float mu = muS[p], rs = rsS[p];
    int ocs = oc ^ (p >> 3);
    u16x8 tv = *(const u16x8*)&tile[p * 256 + ocs * 8];
    int c0 = oc * 8;
    u16x8 ov;
    #pragma unroll
    for (int e = 0; e < 8; ++e) {
      float v = bf2f((unsigned short)tv[e]);
      ov[e] = f2bf((v - mu) * rs * sG[c0 + e] + sBt[c0 + e]);
    }
    *(u16x8*)&xn[(size_t)(bp0 + p) * 256 + c0] = ov;
  }
}

// ---------------- MFMA GEMM: C[M,N] = A[M,256] * B[N,256]^T ----------------
// Flat grid, XCD-aware swizzle: blocks sharing one A m-tile land on one XCD
// (flat%8 = XCD on MI355X round-robin dispatch) -> A re-reads hit L2.
// NT = number of 128-wide n-tiles (6 for qkv, 2 for proj).
template<int EPI, int NT>
__global__ __launch_bounds__(256) void k_gemm_mfma(
    const unsigned short* __restrict__ A,
    const unsigned short* __restrict__ Bw,
    unsigned short* __restrict__ Cout,
    const float* __restrict__ bias,
    const unsigned short* __restrict__ subB,
    int ldc)
{
  __shared__ __align__(16) unsigned short As[128 * 32];
  __shared__ __align__(16) unsigned short Bs[128 * 32];
  __shared__ __align__(16) unsigned short Cs[64 * 136];
  int flat = blockIdx.x;
  int xcd = flat & 7;
  int l = flat >> 3;
  int ml = l / NT;
  int nn = l - ml * NT;
  int m0 = (xcd * 32 + ml) * 128;
  int n0 = nn * 128;
  int tid = threadIdx.x;
  int wv = tid >> 6;
  int lane = tid & 63;
  int mw = (wv >> 1) * 64, nw = (wv & 1) * 64;
  int r = lane & 15, q = lane >> 4;

  int seg0 = wv * 2;
  int srow0 = seg0 * 16 + (lane >> 2);
  int scol = (lane & 3) * 8;
  const unsigned short* ga0 = A  + (size_t)(m0 + srow0) * 256 + scol;
  const unsigned short* ga1 = ga0 + 16 * 256;
  const unsigned short* gb0 = Bw + (size_t)(n0 + srow0) * 256 + scol;
  const unsigned short* gb1 = gb0 + 16 * 256;
  unsigned short* la0 = &As[seg0 * 512];
  unsigned short* la1 = la0 + 512;
  unsigned short* lb0 = &Bs[seg0 * 512];
  unsigned short* lb1 = lb0 + 512;

  f32x4 acc[4][4];
  #pragma unroll
  for (int i = 0; i < 4; ++i)
    #pragma unroll
    for (int j = 0; j < 4; ++j)
      acc[i][j] = (f32x4){0.f, 0.f, 0.f, 0.f};

  for (int k0 = 0; k0 < 256; k0 += 32) {
    GLD_LDS16(ga0 + k0, la0);
    GLD_LDS16(ga1 + k0, la1);
    GLD_LDS16(gb0 + k0, lb0);
    GLD_LDS16(gb1 + k0, lb1);
    __syncthreads();
    bf16x8 af[4], bfr[4];
    #pragma unroll
    for (int mt = 0; mt < 4; ++mt)
      af[mt] = *(const bf16x8*)&As[(mw + mt * 16 + r) * 32 + q * 8];
    #pragma unroll
    for (int nt = 0; nt < 4; ++nt)
      bfr[nt] = *(const bf16x8*)&Bs[(nw + nt * 16 + r) * 32 + q * 8];
    #pragma unroll
    for (int mt = 0; mt < 4; ++mt)
      #pragma unroll
      for (int nt = 0; nt < 4; ++nt)
        acc[mt][nt] = __builtin_amdgcn_mfma_f32_16x16x32_bf16(af[mt], bfr[nt], acc[mt][nt], 0, 0, 0);
    __syncthreads();
  }

  int b = m0 >> 12;
  int nn0 = m0 & 4095;
  #pragma unroll
  for (int pass = 0; pass < 2; ++pass) {
    __syncthreads();
    if (EPI == 0) {
      if ((wv >> 1) == pass) {
        #pragma unroll
        for (int mt = 0; mt < 4; ++mt) {
          int lr = mt * 16 + q * 4;
          #pragma unroll
          for (int nt = 0; nt < 4; ++nt) {
            int col = nw + nt * 16 + r;
            #pragma unroll
            for (int rr = 0; rr < 4; ++rr)
              Cs[(lr + rr) * 136 + col] = f2bf(acc[mt][nt][rr]);
          }
        }
      }
    } else {
      if ((wv & 1) == pass) {
        #pragma unroll
        for (int nt = 0; nt < 4; ++nt) {
          int lr = nt * 16 + r;
          #pragma unroll
          for (int mt = 0; mt < 4; ++mt) {
            int pc = mw + mt * 16 + q * 4;
            #pragma unroll
            for (int rr = 0; rr < 4; ++rr)
              Cs[lr * 136 + pc + rr] = f2bf(acc[mt][nt][rr]);
          }
        }
      }
    }
    __syncthreads();
    if (EPI == 0) {
      #pragma unroll
      for (int cc = 0; cc < 4; ++cc) {
        int ch = cc * 256 + tid;
        int row = ch >> 4, cg = ch & 15;
        u16x8 cv = *(const u16x8*)&Cs[row * 136 + cg * 8];
        int m = m0 + pass * 64 + row;
        *(u16x8*)&Cout[(size_t)m * ldc + n0 + cg * 8] = cv;
      }
    } else {
      #pragma unroll
      for (int cc = 0; cc < 4; ++cc) {
        int ch = cc * 256 + tid;
        int row = ch >> 4, cg = ch & 15;
        u16x8 cv = *(const u16x8*)&Cs[row * 136 + cg * 8];
        int c = n0 + pass * 64 + row;
        size_t idx = ((size_t)(b * 256 + c)) * 4096 + nn0 + cg * 8;
        u16x8 sv = *(const u16x8*)&subB[idx];
        float bb = bias[c];
        u16x8 ov;
        #pragma unroll
        for (int e = 0; e < 8; ++e)
          ov[e] = f2bf(bf2f((unsigned short)cv[e]) + bb + bf2f((unsigned short)sv[e]));
        *(u16x8*)&Cout[idx] = ov;
      }
    }
  }
}

// ---------------- kernel 3: dilated local attention ----------------
__global__ __launch_bounds__(256) void k_attn(
    const unsigned short* __restrict__ qkv,   // [NPOS, 768] bf16
    unsigned short* __restrict__ y)           // [NPOS, 256] bf16
{
  int t = threadIdx.x;
  int sub = t >> 2;
  int lane4 = t & 3;
  int item = blockIdx.x * 64 + sub;
  int ih = item & 7;
  int p = item >> 3;
  int i = ih >> 1, h = ih & 1;
  int dil = i + 1;
  int b = p >> 12;
  int n = p & 4095;
  int py = n >> 6, px = n & 63;
  int off = i * 64 + h * 32 + lane4 * 8;
  const unsigned short* base = qkv + off;

  uint4 qw = *(const uint4*)(base + (size_t)p * 768);
  float q0 = blo(qw.x), q1 = bhi(qw.x), q2 = blo(qw.y), q3 = bhi(qw.y),
        q4 = blo(qw.z), q5 = bhi(qw.z), q6 = blo(qw.w), q7 = bhi(qw.w);

  int pj[9];
  #pragma unroll
  for (int j = 0; j < 9; ++j) {
    int ny = py + (j / 3 - 1) * dil;
    int nx = px + (j % 3 - 1) * dil;
    bool ok = ((unsigned)ny < 64u) && ((unsigned)nx < 64u);
    pj[j] = ok ? ((b << 12) + (ny << 6) + nx) : -1;
  }

  float sc[9];
  #pragma unroll
  for (int j = 0; j < 9; ++j) {
    float s = 0.f;
    if (pj[j] >= 0) {
      uint4 kw = *(const uint4*)(base + 256 + (size_t)pj[j] * 768);
      s  = q0 * blo(kw.x) + q1 * bhi(kw.x);
      s += q2 * blo(kw.y) + q3 * bhi(kw.y);
      s += q4 * blo(kw.z) + q5 * bhi(kw.z);
      s += q6 * blo(kw.w) + q7 * bhi(kw.w);
    }
    s += __shfl_xor(s, 1, 4);
    s += __shfl_xor(s, 2, 4);
    sc[j] = s * SCALE_;             // zero-pad taps -> score exactly 0
  }

  float mx = sc[0];
  #pragma unroll
  for (int j = 1; j < 9; ++j) mx = fmaxf(mx, sc[j]);
  float e[9], ssum = 0.f;
  #pragma unroll
  for (int j = 0; j < 9; ++j) { e[j] = __expf(sc[j] - mx); ssum += e[j]; }
  float inv = 1.f / ssum;

  float o0 = 0.f, o1 = 0.f, o2 = 0.f, o3 = 0.f, o4 = 0.f, o5 = 0.f, o6 = 0.f, o7 = 0.f;
  #pragma unroll
  for (int j = 0; j < 9; ++j) {
    if (pj[j] >= 0) {
      float w = e[j] * inv;
      uint4 vw = *(const uint4*)(base + 512 + (size_t)pj[j] * 768);
      o0 += w * blo(vw.x); o1 += w * bhi(vw.x);
      o2 += w * blo(vw.y); o3 += w * bhi(vw.y);
      o4 += w * blo(vw.z); o5 += w * bhi(vw.z);
      o6 += w * blo(vw.w); o7 += w * bhi(vw.w);
    }
  }

  u16x8 ov;
  ov[0] = f2bf(o0); ov[1] = f2bf(o1); ov[2] = f2bf(o2); ov[3] = f2bf(o3);
  ov[4] = f2bf(o4); ov[5] = f2bf(o5); ov[6] = f2bf(o6); ov[7] = f2bf(o7);
  *(u16x8*)(y + (size_t)p * 256 + off) = ov;
}

// ---------------- kernel 5: per-(b,c) 64x64x64 MFMA matmul, dup output ----
// o[i,j] = sum_k vi[i,k] * div[k,j]; A=Vs row-major, B=Ds transposed [j][k].
// Row stride 72 ushorts = 144 B = 9x16B: b128-aligned, conflict-free frags.
__global__ __launch_bounds__(256) void k_bmm(
    const unsigned short* __restrict__ viB,
    const unsigned short* __restrict__ divmB,
    float* __restrict__ out)
{
  __shared__ __align__(16) unsigned short Vs[64 * 72];
  __shared__ __align__(16) unsigned short Ds[64 * 72];
  int bc = blockIdx.x;
  size_t base = (size_t)bc * 4096;
  int t = threadIdx.x;
  {
    int flat = t * 16;
    int row = flat >> 6, col = flat & 63;   // row: i for vi / k for div
    u16x8 v0 = *(const u16x8*)&viB[base + flat];
    u16x8 v1 = *(const u16x8*)&viB[base + flat + 8];
    *(u16x8*)&Vs[row * 72 + col] = v0;
    *(u16x8*)&Vs[row * 72 + col + 8] = v1;
    u16x8 d0 = *(const u16x8*)&divmB[base + flat];
    u16x8 d1 = *(const u16x8*)&divmB[base + flat + 8];
    #pragma unroll
    for (int e = 0; e < 8; ++e) {
      Ds[(col + e) * 72 + row] = (unsigned short)d0[e];       // Ds[j][k]
      Ds[(col + 8 + e) * 72 + row] = (unsigned short)d1[e];
    }
  }
  __syncthreads();
  int w = t >> 6, lane = t & 63;
  int r = lane & 15, q = lane >> 4;
  int wi = (w >> 1) * 32, wj = (w & 1) * 32;
  f32x4 acc[2][2];
  #pragma unroll
  for (int i = 0; i < 2; ++i)
    #pragma unroll
    for (int j = 0; j < 2; ++j)
      acc[i][j] = (f32x4){0.f, 0.f, 0.f, 0.f};
  #pragma unroll
  for (int ks = 0; ks < 2; ++ks) {
    bf16x8 a[2], bfr[2];
    #pragma unroll
    for (int ti = 0; ti < 2; ++ti)
      a[ti] = *(const bf16x8*)&Vs[(wi + ti * 16 + r) * 72 + ks * 32 + q * 8];
    #pragma unroll
    for (int tj = 0; tj < 2; ++tj)
      bfr[tj] = *(const bf16x8*)&Ds[(wj + tj * 16 + r) * 72 + ks * 32 + q * 8];
    #pragma unroll
    for (int ti = 0; ti < 2; ++ti)
      #pragma unroll
      for (int tj = 0; tj < 2; ++tj)
        acc[ti][tj] = __builtin_amdgcn_mfma_f32_16x16x32_bf16(a[ti], bfr[tj], acc[ti][tj], 0, 0, 0);
  }
  #pragma unroll
  for (int ti = 0; ti < 2; ++ti)
    #pragma unroll
    for (int tj = 0; tj < 2; ++tj)
      #pragma unroll
      for (int rr = 0; rr < 4; ++rr) {
        int row = wi + ti * 16 + q * 4 + rr;
        int col = wj + tj * 16 + r;
        float v = acc[ti][tj][rr];
        out[base + row * 64 + col] = v;
        out[8388608ull + base + row * 64 + col] = v;
      }
}

extern "C" void kernel_launch(void* const* d_in, const int* in_sizes, int n_in,
                              void* d_out, int out_size, void* d_ws, size_t ws_size,
                              hipStream_t stream) {
  const float* vi     = (const float*)d_in[0];
  const float* ir     = (const float*)d_in[1];
  const float* w_qkv  = (const float*)d_in[2];
  const float* proj_w = (const float*)d_in[3];
  const float* proj_b = (const float*)d_in[4];
  const float* ln_g   = (const float*)d_in[5];
  const float* ln_b   = (const float*)d_in[6];
  float* out = (float*)d_out;
  char* ws = (char*)d_ws;
  unsigned short* subB = (unsigned short*)(ws);                // 16.8 MB BCHW bf16
  unsigned short* qkvb = (unsigned short*)(ws + 16777216);     // 50.3 MB [NPOS,768]
  float2* partials     = (float2*)(ws + 16777216);             // 2 MB, consumed before qkvb written
  unsigned short* divmB= (unsigned short*)(ws + 16777216);     // reuse, 16.8 MB BCHW
  unsigned short* xnb  = (unsigned short*)(ws + 67108864);     // 16.8 MB [NPOS,256]
  unsigned short* yb   = (unsigned short*)(ws + 83886080);     // 16.8 MB [NPOS,256]
  unsigned short* viB  = (unsigned short*)(ws + 100663296);    // 16.8 MB BCHW bf16
  unsigned short* wqb  = (unsigned short*)(ws + 117440512);    // [768,256] bf16
  unsigned short* pwb  = wqb + 196608;                         // [256,256] bf16

  k_stream<<<1280, 256, 0, stream>>>(vi, ir, w_qkv, proj_w, wqb, subB, viB, partials);
  k_lnt<<<512, 256, 0, stream>>>(subB, partials, ln_g, ln_b, xnb);
  k_gemm_mfma<0, 6><<<1536, 256, 0, stream>>>(xnb, wqb, qkvb, nullptr, nullptr, 768);
  k_attn<<<4096, 256, 0, stream>>>(qkvb, yb);
  k_gemm_mfma<1, 2><<<512, 256, 0, stream>>>(yb, pwb, divmB, proj_b, subB, 0);
  k_bmm<<<2048, 256, 0, stream>>>(viB, divmB, out);
}